// Round 17
// baseline (823.816 us; speedup 1.0000x reference)
//
#include <hip/hip_runtime.h>
#include <hip/hip_bf16.h>

// ShiftWindowMSA fully-fused kernel for MI355X (gfx950).
// R17: LDS 144->72 KB so TWO blocks co-reside per CU (cross-block overlap of
// gather/GEMM/store phases). 12 waves (wave = head). Wave scratch = 2 KB
// (single-buffered staging; Q/K bounced in two 2KB rounds). V/P/fp32-out
// bounce through the wave's 4KB slice of the (dead) A-region, guarded by
// barriers B4/B5a/B6. Sequential k-GEMM then v-GEMM. launch_bounds(768,6).

typedef __attribute__((ext_vector_type(8))) short short8;
typedef __attribute__((ext_vector_type(4))) float floatx4;

#define MFMA16(a, b, c) __builtin_amdgcn_mfma_f32_16x16x32_bf16(a, b, c, 0, 0, 0)

__device__ __forceinline__ short f2bf(float f) {
    __hip_bfloat16 h = __float2bfloat16(f);
    return *reinterpret_cast<short*>(&h);
}

// packed fp32->bf16 RNE
__device__ __forceinline__ unsigned cvt2bf(float lo, float hi) {
    unsigned r;
    asm("v_cvt_pk_bf16_f32 %0, %1, %2" : "=v"(r) : "v"(lo), "v"(hi));
    return r;
}

__device__ __forceinline__ void glds16(const void* g, void* l) {
    __builtin_amdgcn_global_load_lds(
        (const __attribute__((address_space(1))) void*)g,
        (__attribute__((address_space(3))) void*)l, 16, 0, 0);
}

__device__ __forceinline__ void lds_fence() {
    asm volatile("s_waitcnt lgkmcnt(0)" ::: "memory");
    __builtin_amdgcn_sched_barrier(0);
}

// ---------------- prep kernels ----------------

__global__ __launch_bounds__(256) void prep_wt(const float* __restrict__ Wqkv,
                                               const float* __restrict__ Wskip,
                                               short* __restrict__ Wt) {
    int tid = blockIdx.x * 256 + threadIdx.x;  // 384*144 = 55296
    if (tid >= 384 * 144) return;
    int k = tid / 144;
    int n8 = (tid % 144) * 8;
#pragma unroll
    for (int e = 0; e < 8; e++) {
        int n = n8 + e;
        float v = (n < 768) ? Wqkv[k * 768 + n]
                            : Wskip[k * 384 + (n - 768)] * 0.17677669529663687f;
        Wt[(size_t)n * 384 + k] = f2bf(v);
    }
}

__global__ __launch_bounds__(256) void prep_wtp(const float* __restrict__ Wproj,
                                                short* __restrict__ WtP) {
    int tid = blockIdx.x * 256 + threadIdx.x;  // 384*48 = 18432
    if (tid >= 384 * 48) return;
    int k = tid / 48;
    int n8 = (tid % 48) * 8;
#pragma unroll
    for (int e = 0; e < 8; e++) {
        int n = n8 + e;
        WtP[(size_t)n * 384 + k] = f2bf(Wproj[k * 384 + n]);
    }
}

__global__ __launch_bounds__(256) void prep_bias(const float* __restrict__ rpb,
                                                 float* __restrict__ bias64) {
    int tid = blockIdx.x * 256 + threadIdx.x;  // 12*64*64 = 49152
    if (tid >= 49152) return;
    int h = tid >> 12;
    int rem = tid & 4095;
    int i = rem >> 6, kk = rem & 63;
    int j = 63 - kk;
    int ridx = 15 * (i >> 3) + (i & 7) + 15 * (j >> 3) + (j & 7);
    bias64[tid] = rpb[ridx * 12 + h];
}

// ---------------- fused per-window kernel ----------------
__global__ __launch_bounds__(768, 6) void fused_win(
    const float* __restrict__ xq, const float* __restrict__ xs,
    const short* __restrict__ Wt, const short* __restrict__ WtP,
    const float* __restrict__ bqkv, const float* __restrict__ bskip,
    const float* __restrict__ bproj, const float* __restrict__ bias64,
    float* __restrict__ out) {
    __shared__ short smem[36864];  // A [0,24576); wave scratch @24576+wid*1024

    const int win = blockIdx.x;
    const int tid = threadIdx.x, lane = tid & 63, wid = tid >> 6;  // wid = head
    const int l15 = lane & 15, g4 = lane >> 4;
    const int al7 = l15 & 7;
    const int brd = (g4 ^ ((l15 ^ (l15 >> 2)) & 3)) * 8;

    const int b_img = win / 144, wr = win % 144;
    const int wy = wr / 12, wx = wr % 12;

    // gather mapping: 64 rows x 12 threads (4 chunks of 16B each)
    const int gr = tid / 12, gj = tid - gr * 12;
    int gyy = wy * 8 + (gr >> 3) + 4; if (gyy >= 96) gyy -= 96;
    int gxx = wx * 8 + (gr & 7) + 4;  if (gxx >= 96) gxx -= 96;
    const size_t grow = ((size_t)b_img * 9216 + gyy * 96 + gxx) * 384;
    short* lrow = smem + gr * 384;
    const int gr7 = gr & 7;

    // B strip staging (32 rows x 32 k per step = 2 glds of 1 KB); 1 buffer
    const int swst = ((lane >> 2) ^ (lane >> 4)) & 3;
    int bso[2];
#pragma unroll
    for (int j = 0; j < 2; j++)
        bso[j] = (j * 16 + (lane >> 2)) * 384 + (((lane & 3) ^ swst) * 8);
    short* wsc = smem + 24576 + wid * 1024;  // wave scratch (2 KB)
    short* pA  = smem + wid * 2048;          // wave's A-region slice (4 KB)

    const short* sK = Wt + (size_t)(wid * 32) * 384;
    const short* sV = Wt + (size_t)(384 + wid * 32) * 384;
    const short* sQ = Wt + (size_t)(768 + wid * 32) * 384;
    const short* sP = WtP + (size_t)(wid * 32) * 384;

    // ---- phase 1: q prologue + gather skip + early xq reg loads + B1 ----
#pragma unroll
    for (int j = 0; j < 2; j++) glds16(sQ + bso[j], wsc + j * 512);
    {
        const float* rb = xs + grow;
#pragma unroll
        for (int cc = 0; cc < 4; cc++) {
            int c = gj * 4 + cc;
            float4 f0 = *(const float4*)(rb + c * 8);
            float4 f1 = *(const float4*)(rb + c * 8 + 4);
            uint4 u;
            u.x = cvt2bf(f0.x, f0.y); u.y = cvt2bf(f0.z, f0.w);
            u.z = cvt2bf(f1.x, f1.y); u.w = cvt2bf(f1.z, f1.w);
            *(uint4*)(lrow + ((c ^ gr7) * 8)) = u;
        }
    }
    float4 xr[8];  // xq rows in flight during q-GEMM
    {
        const float* rb = xq + grow;
#pragma unroll
        for (int cc = 0; cc < 4; cc++) {
            xr[cc * 2]     = *(const float4*)(rb + (gj * 4 + cc) * 8);
            xr[cc * 2 + 1] = *(const float4*)(rb + (gj * 4 + cc) * 8 + 4);
        }
    }
    __syncthreads();  // B1

    // ---- q-GEMM (swapped; 12 steps; single-buffered staging) ----
    floatx4 aq[2][4];
#pragma unroll
    for (int a = 0; a < 2; a++)
#pragma unroll
        for (int b = 0; b < 4; b++)
#pragma unroll
            for (int r = 0; r < 4; r++) aq[a][b][r] = 0.f;
#pragma unroll
    for (int kt = 0; kt < 12; ++kt) {
        asm volatile("s_waitcnt vmcnt(0)" ::: "memory");
        const int choff = ((kt * 4 + g4) ^ al7) * 8;
        short8 af[4], bq[2];
#pragma unroll
        for (int b = 0; b < 4; b++)
            af[b] = *(const short8*)(smem + (b * 16 + l15) * 384 + choff);
#pragma unroll
        for (int a = 0; a < 2; a++)
            bq[a] = *(const short8*)(wsc + (a * 16 + l15) * 32 + brd);
        __builtin_amdgcn_sched_barrier(0);
        asm volatile("s_waitcnt lgkmcnt(0)" ::: "memory");
        if (kt < 11) {
            int ko = (kt + 1) * 32;
#pragma unroll
            for (int j = 0; j < 2; j++) glds16(sQ + bso[j] + ko, wsc + j * 512);
        }
        __builtin_amdgcn_sched_barrier(0);
#pragma unroll
        for (int a = 0; a < 2; a++)
#pragma unroll
            for (int b = 0; b < 4; b++)
                aq[a][b] = MFMA16(bq[a], af[b], aq[a][b]);
    }

    // ---- Q bounce: two 2KB rounds through scratch -> qf ----
    const float scl = 0.17677669529663687f;
    short8 qf[4];
#pragma unroll
    for (int jq = 0; jq < 2; jq++) {
#pragma unroll
        for (int a = 0; a < 2; a++) {
            float4 bv = *(const float4*)(bskip + wid * 32 + a * 16 + g4 * 4);
#pragma unroll
            for (int bb = 0; bb < 2; bb++) {
                int b = jq * 2 + bb;
                uint2 pk;
                pk.x = cvt2bf(aq[a][b][0] + bv.x * scl, aq[a][b][1] + bv.y * scl);
                pk.y = cvt2bf(aq[a][b][2] + bv.z * scl, aq[a][b][3] + bv.w * scl);
                int lr = bb * 16 + l15;
                int phys = (a * 2 + (g4 >> 1)) ^ (l15 & 3);
                *(uint2*)(wsc + lr * 32 + phys * 8 + (g4 & 1) * 4) = pk;
            }
        }
        lds_fence();
#pragma unroll
        for (int nn = 0; nn < 2; nn++)
            qf[jq * 2 + nn] = *(const short8*)(wsc + (nn * 16 + l15) * 32 +
                                               ((g4 ^ (l15 & 3)) * 8));
        lds_fence();
    }

    // ---- k prologue + B2 + xq regs -> A + B3 ----
#pragma unroll
    for (int j = 0; j < 2; j++) glds16(sK + bso[j], wsc + j * 512);
    __syncthreads();  // B2: all waves done reading A(skip)
#pragma unroll
    for (int cc = 0; cc < 4; cc++) {
        int c = gj * 4 + cc;
        uint4 u;
        u.x = cvt2bf(xr[cc * 2].x, xr[cc * 2].y);
        u.y = cvt2bf(xr[cc * 2].z, xr[cc * 2].w);
        u.z = cvt2bf(xr[cc * 2 + 1].x, xr[cc * 2 + 1].y);
        u.w = cvt2bf(xr[cc * 2 + 1].z, xr[cc * 2 + 1].w);
        *(uint4*)(lrow + ((c ^ gr7) * 8)) = u;
    }
    __syncthreads();  // B3

    // ---- k-GEMM (swapped) ----
    floatx4 ak[2][4];
#pragma unroll
    for (int a = 0; a < 2; a++)
#pragma unroll
        for (int b = 0; b < 4; b++)
#pragma unroll
            for (int r = 0; r < 4; r++) ak[a][b][r] = 0.f;
#pragma unroll
    for (int kt = 0; kt < 12; ++kt) {
        asm volatile("s_waitcnt vmcnt(0)" ::: "memory");
        const int choff = ((kt * 4 + g4) ^ al7) * 8;
        short8 af[4], bk[2];
#pragma unroll
        for (int b = 0; b < 4; b++)
            af[b] = *(const short8*)(smem + (b * 16 + l15) * 384 + choff);
#pragma unroll
        for (int a = 0; a < 2; a++)
            bk[a] = *(const short8*)(wsc + (a * 16 + l15) * 32 + brd);
        __builtin_amdgcn_sched_barrier(0);
        asm volatile("s_waitcnt lgkmcnt(0)" ::: "memory");
        if (kt < 11) {
            int ko = (kt + 1) * 32;
#pragma unroll
            for (int j = 0; j < 2; j++) glds16(sK + bso[j] + ko, wsc + j * 512);
        }
        __builtin_amdgcn_sched_barrier(0);
#pragma unroll
        for (int a = 0; a < 2; a++)
#pragma unroll
            for (int b = 0; b < 4; b++)
                ak[a][b] = MFMA16(bk[a], af[b], ak[a][b]);
    }

    // ---- K bounce: two 2KB rounds through scratch -> kf ----
    short8 kf[4];
#pragma unroll
    for (int jq = 0; jq < 2; jq++) {
#pragma unroll
        for (int a = 0; a < 2; a++) {
            float4 bv = *(const float4*)(bqkv + wid * 32 + a * 16 + g4 * 4);
#pragma unroll
            for (int bb = 0; bb < 2; bb++) {
                int b = jq * 2 + bb;
                uint2 pk;
                pk.x = cvt2bf(ak[a][b][0] + bv.x, ak[a][b][1] + bv.y);
                pk.y = cvt2bf(ak[a][b][2] + bv.z, ak[a][b][3] + bv.w);
                int lr = bb * 16 + l15;
                int phys = (a * 2 + (g4 >> 1)) ^ (l15 & 3);
                *(uint2*)(wsc + lr * 32 + phys * 8 + (g4 & 1) * 4) = pk;
            }
        }
        lds_fence();
#pragma unroll
        for (int nn = 0; nn < 2; nn++)
            kf[jq * 2 + nn] = *(const short8*)(wsc + (nn * 16 + l15) * 32 +
                                               ((g4 ^ (l15 & 3)) * 8));
        lds_fence();
    }

    // ---- v prologue + v-GEMM (unswapped) ----
#pragma unroll
    for (int j = 0; j < 2; j++) glds16(sV + bso[j], wsc + j * 512);
    floatx4 av[2][4];
#pragma unroll
    for (int a = 0; a < 2; a++)
#pragma unroll
        for (int b = 0; b < 4; b++)
#pragma unroll
            for (int r = 0; r < 4; r++) av[a][b][r] = 0.f;
#pragma unroll
    for (int kt = 0; kt < 12; ++kt) {
        asm volatile("s_waitcnt vmcnt(0)" ::: "memory");
        const int choff = ((kt * 4 + g4) ^ al7) * 8;
        short8 af[4], bv2[2];
#pragma unroll
        for (int b = 0; b < 4; b++)
            af[b] = *(const short8*)(smem + (b * 16 + l15) * 384 + choff);
#pragma unroll
        for (int a = 0; a < 2; a++)
            bv2[a] = *(const short8*)(wsc + (a * 16 + l15) * 32 + brd);
        __builtin_amdgcn_sched_barrier(0);
        asm volatile("s_waitcnt lgkmcnt(0)" ::: "memory");
        if (kt < 11) {
            int ko = (kt + 1) * 32;
#pragma unroll
            for (int j = 0; j < 2; j++) glds16(sV + bso[j] + ko, wsc + j * 512);
        }
        __builtin_amdgcn_sched_barrier(0);
#pragma unroll
        for (int a = 0; a < 2; a++)
#pragma unroll
            for (int b = 0; b < 4; b++)
                av[a][b] = MFMA16(af[b], bv2[a], av[a][b]);
    }
    __syncthreads();  // B4: all waves done reading A(query)

    // ---- V bounce: V^T[32d][64t] swizzled into A-slice -> vf ----
#pragma unroll
    for (int a = 0; a < 2; a++) {
        float bvs = bqkv[384 + wid * 32 + a * 16 + l15];
#pragma unroll
        for (int b = 0; b < 4; b++) {
            uint2 pk;
            pk.x = cvt2bf(av[a][b][0] + bvs, av[a][b][1] + bvs);
            pk.y = cvt2bf(av[a][b][2] + bvs, av[a][b][3] + bvs);
            int tch = b * 2 + (g4 >> 1);
            *(uint2*)(pA + (a * 16 + l15) * 64 +
                      ((tch ^ (l15 & 7)) * 8) + (g4 & 1) * 4) = pk;
        }
    }
    lds_fence();
    short8 vf[2][2];
#pragma unroll
    for (int ma = 0; ma < 2; ma++)
#pragma unroll
        for (int ks = 0; ks < 2; ks++)
            vf[ma][ks] = *(const short8*)(pA + (ma * 16 + l15) * 64 +
                                          (((ks * 4 + g4) ^ (l15 & 7)) * 8));
    lds_fence();

    // ---- attention: S^T = mfma(K,Q) ----
    floatx4 st[4][4];
#pragma unroll
    for (int mi = 0; mi < 4; mi++)
#pragma unroll
        for (int nj = 0; nj < 4; nj++)
#pragma unroll
            for (int r = 0; r < 4; r++) st[mi][nj][r] = 0.f;
#pragma unroll
    for (int mi = 0; mi < 4; mi++)
#pragma unroll
        for (int nj = 0; nj < 4; nj++)
            st[mi][nj] = MFMA16(kf[mi], qf[nj], st[mi][nj]);

    const float* bb = bias64 + wid * 4096;
#pragma unroll
    for (int nj = 0; nj < 4; nj++) {
        int i = nj * 16 + l15;
#pragma unroll
        for (int mi = 0; mi < 4; mi++) {
            floatx4 b4 = *(const floatx4*)(bb + i * 64 + mi * 16 + g4 * 4);
            st[mi][nj] += b4;
        }
    }

    if (wy == 11 || wx == 11) {
        int wy11 = (wy == 11), wx11 = (wx == 11);
        int ri[4];
#pragma unroll
        for (int nj = 0; nj < 4; nj++) {
            int t = nj * 16 + l15;
            int hh = wy11 ? (((t >> 3) >= 4) ? 2 : 1) : 0;
            int ww = wx11 ? (((t & 7) >= 4) ? 2 : 1) : 0;
            ri[nj] = hh * 3 + ww;
        }
#pragma unroll
        for (int mi = 0; mi < 4; mi++)
#pragma unroll
            for (int r = 0; r < 4; r++) {
                int t = mi * 16 + g4 * 4 + r;
                int hh = wy11 ? (((t >> 3) >= 4) ? 2 : 1) : 0;
                int ww = wx11 ? (((t & 7) >= 4) ? 2 : 1) : 0;
                int rk = hh * 3 + ww;
#pragma unroll
                for (int nj = 0; nj < 4; nj++)
                    if (rk != ri[nj]) st[mi][nj][r] -= 100.0f;
            }
    }

    float rden[4];
#pragma unroll
    for (int nj = 0; nj < 4; nj++) {
        float m = -1e30f;
#pragma unroll
        for (int mi = 0; mi < 4; mi++)
#pragma unroll
            for (int r = 0; r < 4; r++) m = fmaxf(m, st[mi][nj][r]);
        m = fmaxf(m, __shfl_xor(m, 16));
        m = fmaxf(m, __shfl_xor(m, 32));
        float s = 0.f;
#pragma unroll
        for (int mi = 0; mi < 4; mi++)
#pragma unroll
            for (int r = 0; r < 4; r++) {
                float p = __expf(st[mi][nj][r] - m);
                st[mi][nj][r] = p;
                s += p;
            }
        s += __shfl_xor(s, 16);
        s += __shfl_xor(s, 32);
        rden[nj] = 1.0f / s;
    }

    // ---- P halves through A-slice + PV ----
    floatx4 o[2][4];
#pragma unroll
    for (int ma = 0; ma < 2; ma++)
#pragma unroll
        for (int nj = 0; nj < 4; nj++)
#pragma unroll
            for (int r = 0; r < 4; r++) o[ma][nj][r] = 0.f;
#pragma unroll
    for (int ks = 0; ks < 2; ks++) {
#pragma unroll
        for (int mm = 0; mm < 2; mm++) {
            int mi = ks * 2 + mm;
#pragma unroll
            for (int nj = 0; nj < 4; nj++) {
                uint2 pk;
                pk.x = cvt2bf(st[mi][nj][0], st[mi][nj][1]);
                pk.y = cvt2bf(st[mi][nj][2], st[mi][nj][3]);
                int phys = (mm * 2 + (g4 >> 1)) ^ (l15 & 3);
                *(uint2*)(pA + (nj * 16 + l15) * 32 + phys * 8 + (g4 & 1) * 4) = pk;
            }
        }
        lds_fence();
        short8 pb[4];
#pragma unroll
        for (int nj = 0; nj < 4; nj++)
            pb[nj] = *(const short8*)(pA + (nj * 16 + l15) * 32 +
                                      ((g4 ^ (l15 & 3)) * 8));
#pragma unroll
        for (int ma = 0; ma < 2; ma++)
#pragma unroll
            for (int nj = 0; nj < 4; nj++)
                o[ma][nj] = MFMA16(vf[ma][ks], pb[nj], o[ma][nj]);
        lds_fence();
    }

    // ---- proj prologue (wave-private scratch) ----
#pragma unroll
    for (int j = 0; j < 2; j++) glds16(sP + bso[j], wsc + j * 512);

    __syncthreads();  // B5a: all waves done with their P-slices

    // ---- out -> A-region (chunk-swizzled [t][384]) ----
#pragma unroll
    for (int ma = 0; ma < 2; ma++)
#pragma unroll
        for (int nj = 0; nj < 4; nj++) {
            int i = nj * 16 + l15;
            uint2 pk;
            pk.x = cvt2bf(o[ma][nj][0] * rden[nj], o[ma][nj][1] * rden[nj]);
            pk.y = cvt2bf(o[ma][nj][2] * rden[nj], o[ma][nj][3] * rden[nj]);
            int ch = wid * 4 + ma * 2 + (g4 >> 1);
            *(uint2*)(smem + i * 384 + ((ch ^ (i & 7)) * 8) + (g4 & 1) * 4) = pk;
        }
    __syncthreads();  // B5

    // ---- proj GEMM (swapped; single-buffered staging) ----
    floatx4 ap[2][4];
#pragma unroll
    for (int a = 0; a < 2; a++)
#pragma unroll
        for (int b = 0; b < 4; b++)
#pragma unroll
            for (int r = 0; r < 4; r++) ap[a][b][r] = 0.f;
#pragma unroll
    for (int kt = 0; kt < 12; ++kt) {
        asm volatile("s_waitcnt vmcnt(0)" ::: "memory");
        const int choff = ((kt * 4 + g4) ^ al7) * 8;
        short8 af[4], bp[2];
#pragma unroll
        for (int b = 0; b < 4; b++)
            af[b] = *(const short8*)(smem + (b * 16 + l15) * 384 + choff);
#pragma unroll
        for (int a = 0; a < 2; a++)
            bp[a] = *(const short8*)(wsc + (a * 16 + l15) * 32 + brd);
        __builtin_amdgcn_sched_barrier(0);
        asm volatile("s_waitcnt lgkmcnt(0)" ::: "memory");
        if (kt < 11) {
            int ko = (kt + 1) * 32;
#pragma unroll
            for (int j = 0; j < 2; j++) glds16(sP + bso[j] + ko, wsc + j * 512);
        }
        __builtin_amdgcn_sched_barrier(0);
#pragma unroll
        for (int a = 0; a < 2; a++)
#pragma unroll
            for (int b = 0; b < 4; b++)
                ap[a][b] = MFMA16(bp[a], af[b], ap[a][b]);
    }
    __syncthreads();  // B6: all waves done reading A(out)

    // ---- fp32 out: two rounds through A-slice -> full-line stores ----
    float* fsc = (float*)pA;  // [32][32] fp32 per round
#pragma unroll
    for (int h = 0; h < 2; h++) {
#pragma unroll
        for (int a = 0; a < 2; a++) {
            float4 bv = *(const float4*)(bproj + wid * 32 + a * 16 + g4 * 4);
#pragma unroll
            for (int bb = 0; bb < 2; bb++) {
                int b = h * 2 + bb;
                int lr = bb * 16 + l15;
                int phys = (a * 4 + g4) ^ (lr & 7);
                floatx4 ov = ap[a][b];
                ov[0] += bv.x; ov[1] += bv.y; ov[2] += bv.z; ov[3] += bv.w;
                *(floatx4*)(fsc + lr * 32 + phys * 4) = ov;
            }
        }
        lds_fence();
        {
            const int r8 = lane >> 3, c8 = lane & 7;
#pragma unroll
            for (int it = 0; it < 4; it++) {
                int lr = it * 8 + r8;
                floatx4 ov = *(const floatx4*)(fsc + lr * 32 + ((c8 ^ r8) * 4));
                int trow = h * 32 + lr;
                int yy = wy * 8 + (trow >> 3) + 4; if (yy >= 96) yy -= 96;
                int xx = wx * 8 + (trow & 7) + 4;  if (xx >= 96) xx -= 96;
                *(floatx4*)(&out[((size_t)b_img * 9216 + yy * 96 + xx) * 384 +
                                 wid * 32 + c8 * 4]) = ov;
            }
        }
        lds_fence();
    }
}

// ---------------- launcher ----------------
extern "C" void kernel_launch(void* const* d_in, const int* in_sizes, int n_in,
                              void* d_out, int out_size, void* d_ws, size_t ws_size,
                              hipStream_t stream) {
    const float* query = (const float*)d_in[0];
    const float* skipq = (const float*)d_in[1];
    const float* Wqkv  = (const float*)d_in[2];
    const float* bqkv  = (const float*)d_in[3];
    const float* Wskip = (const float*)d_in[4];
    const float* bskip = (const float*)d_in[5];
    const float* rpb   = (const float*)d_in[6];
    const float* Wproj = (const float*)d_in[7];
    const float* bproj = (const float*)d_in[8];
    float* out = (float*)d_out;

    int M = in_sizes[0] / 384;   // total tokens = 147456 for B=16
    int nwin = M / 64;           // 2304

    char* ws = (char*)d_ws;
    size_t off = 0;
    auto alloc = [&](size_t bytes) -> void* {
        void* p = ws + off;
        off = (off + bytes + 255) & ~(size_t)255;
        return p;
    };
    short* Wt     = (short*)alloc((size_t)1152 * 384 * 2);
    short* WtP    = (short*)alloc((size_t)384 * 384 * 2);
    float* bias64 = (float*)alloc((size_t)12 * 64 * 64 * 4);
    (void)ws_size;

    hipLaunchKernelGGL(prep_wt, dim3(216), dim3(256), 0, stream, Wqkv, Wskip, Wt);
    hipLaunchKernelGGL(prep_wtp, dim3(72), dim3(256), 0, stream, Wproj, WtP);
    hipLaunchKernelGGL(prep_bias, dim3(192), dim3(256), 0, stream, rpb, bias64);
    hipLaunchKernelGGL(fused_win, dim3(nwin), dim3(768), 0, stream,
                       query, skipq, Wt, WtP, bqkv, bskip, bproj, bias64, out);
}

// Round 18
// 463.253 us; speedup vs baseline: 1.7783x; 1.7783x over previous
//
#include <hip/hip_runtime.h>
#include <hip/hip_bf16.h>

// ShiftWindowMSA fully-fused kernel for MI355X (gfx950).
// R18: R17's 72 KB-LDS layout (2 blocks/CU target) WITHOUT the register-
// squeezing launch bound (R17's (768,6) forced VGPR=40 -> scratch spills,
// 2.4 GB traffic). Natural allocation (~84 VGPR <= 2048/24) + LDS 72 KB give
// 24 waves/CU. xq gathered between B2/B3 (no 32-VGPR early-gather block).
// 12 waves (wave = head); single-buffered staging; A-slice bounces.

typedef __attribute__((ext_vector_type(8))) short short8;
typedef __attribute__((ext_vector_type(4))) float floatx4;

#define MFMA16(a, b, c) __builtin_amdgcn_mfma_f32_16x16x32_bf16(a, b, c, 0, 0, 0)

__device__ __forceinline__ short f2bf(float f) {
    __hip_bfloat16 h = __float2bfloat16(f);
    return *reinterpret_cast<short*>(&h);
}

// packed fp32->bf16 RNE
__device__ __forceinline__ unsigned cvt2bf(float lo, float hi) {
    unsigned r;
    asm("v_cvt_pk_bf16_f32 %0, %1, %2" : "=v"(r) : "v"(lo), "v"(hi));
    return r;
}

__device__ __forceinline__ void glds16(const void* g, void* l) {
    __builtin_amdgcn_global_load_lds(
        (const __attribute__((address_space(1))) void*)g,
        (__attribute__((address_space(3))) void*)l, 16, 0, 0);
}

__device__ __forceinline__ void lds_fence() {
    asm volatile("s_waitcnt lgkmcnt(0)" ::: "memory");
    __builtin_amdgcn_sched_barrier(0);
}

// ---------------- prep kernels ----------------

__global__ __launch_bounds__(256) void prep_wt(const float* __restrict__ Wqkv,
                                               const float* __restrict__ Wskip,
                                               short* __restrict__ Wt) {
    int tid = blockIdx.x * 256 + threadIdx.x;  // 384*144 = 55296
    if (tid >= 384 * 144) return;
    int k = tid / 144;
    int n8 = (tid % 144) * 8;
#pragma unroll
    for (int e = 0; e < 8; e++) {
        int n = n8 + e;
        float v = (n < 768) ? Wqkv[k * 768 + n]
                            : Wskip[k * 384 + (n - 768)] * 0.17677669529663687f;
        Wt[(size_t)n * 384 + k] = f2bf(v);
    }
}

__global__ __launch_bounds__(256) void prep_wtp(const float* __restrict__ Wproj,
                                                short* __restrict__ WtP) {
    int tid = blockIdx.x * 256 + threadIdx.x;  // 384*48 = 18432
    if (tid >= 384 * 48) return;
    int k = tid / 48;
    int n8 = (tid % 48) * 8;
#pragma unroll
    for (int e = 0; e < 8; e++) {
        int n = n8 + e;
        WtP[(size_t)n * 384 + k] = f2bf(Wproj[k * 384 + n]);
    }
}

__global__ __launch_bounds__(256) void prep_bias(const float* __restrict__ rpb,
                                                 float* __restrict__ bias64) {
    int tid = blockIdx.x * 256 + threadIdx.x;  // 12*64*64 = 49152
    if (tid >= 49152) return;
    int h = tid >> 12;
    int rem = tid & 4095;
    int i = rem >> 6, kk = rem & 63;
    int j = 63 - kk;
    int ridx = 15 * (i >> 3) + (i & 7) + 15 * (j >> 3) + (j & 7);
    bias64[tid] = rpb[ridx * 12 + h];
}

// ---------------- fused per-window kernel ----------------
__global__ __launch_bounds__(768) void fused_win(
    const float* __restrict__ xq, const float* __restrict__ xs,
    const short* __restrict__ Wt, const short* __restrict__ WtP,
    const float* __restrict__ bqkv, const float* __restrict__ bskip,
    const float* __restrict__ bproj, const float* __restrict__ bias64,
    float* __restrict__ out) {
    __shared__ short smem[36864];  // A [0,24576); wave scratch @24576+wid*1024

    const int win = blockIdx.x;
    const int tid = threadIdx.x, lane = tid & 63, wid = tid >> 6;  // wid = head
    const int l15 = lane & 15, g4 = lane >> 4;
    const int al7 = l15 & 7;
    const int brd = (g4 ^ ((l15 ^ (l15 >> 2)) & 3)) * 8;

    const int b_img = win / 144, wr = win % 144;
    const int wy = wr / 12, wx = wr % 12;

    // gather mapping: 64 rows x 12 threads (4 chunks of 16B each)
    const int gr = tid / 12, gj = tid - gr * 12;
    int gyy = wy * 8 + (gr >> 3) + 4; if (gyy >= 96) gyy -= 96;
    int gxx = wx * 8 + (gr & 7) + 4;  if (gxx >= 96) gxx -= 96;
    const size_t grow = ((size_t)b_img * 9216 + gyy * 96 + gxx) * 384;
    short* lrow = smem + gr * 384;
    const int gr7 = gr & 7;

    auto gatherA = [&](const float* src) {
        const float* rb = src + grow;
#pragma unroll
        for (int cc = 0; cc < 4; cc++) {
            int c = gj * 4 + cc;
            float4 f0 = *(const float4*)(rb + c * 8);
            float4 f1 = *(const float4*)(rb + c * 8 + 4);
            uint4 u;
            u.x = cvt2bf(f0.x, f0.y); u.y = cvt2bf(f0.z, f0.w);
            u.z = cvt2bf(f1.x, f1.y); u.w = cvt2bf(f1.z, f1.w);
            *(uint4*)(lrow + ((c ^ gr7) * 8)) = u;
        }
    };

    // B strip staging (32 rows x 32 k per step = 2 glds of 1 KB); 1 buffer
    const int swst = ((lane >> 2) ^ (lane >> 4)) & 3;
    int bso[2];
#pragma unroll
    for (int j = 0; j < 2; j++)
        bso[j] = (j * 16 + (lane >> 2)) * 384 + (((lane & 3) ^ swst) * 8);
    short* wsc = smem + 24576 + wid * 1024;  // wave scratch (2 KB)
    short* pA  = smem + wid * 2048;          // wave's A-region slice (4 KB)

    const short* sK = Wt + (size_t)(wid * 32) * 384;
    const short* sV = Wt + (size_t)(384 + wid * 32) * 384;
    const short* sQ = Wt + (size_t)(768 + wid * 32) * 384;
    const short* sP = WtP + (size_t)(wid * 32) * 384;

    // ---- phase 1: q prologue + gather skip + B1 ----
#pragma unroll
    for (int j = 0; j < 2; j++) glds16(sQ + bso[j], wsc + j * 512);
    gatherA(xs);
    __syncthreads();  // B1

    // ---- q-GEMM (swapped; 12 steps; single-buffered staging) ----
    floatx4 aq[2][4];
#pragma unroll
    for (int a = 0; a < 2; a++)
#pragma unroll
        for (int b = 0; b < 4; b++)
#pragma unroll
            for (int r = 0; r < 4; r++) aq[a][b][r] = 0.f;
#pragma unroll
    for (int kt = 0; kt < 12; ++kt) {
        asm volatile("s_waitcnt vmcnt(0)" ::: "memory");
        const int choff = ((kt * 4 + g4) ^ al7) * 8;
        short8 af[4], bq[2];
#pragma unroll
        for (int b = 0; b < 4; b++)
            af[b] = *(const short8*)(smem + (b * 16 + l15) * 384 + choff);
#pragma unroll
        for (int a = 0; a < 2; a++)
            bq[a] = *(const short8*)(wsc + (a * 16 + l15) * 32 + brd);
        __builtin_amdgcn_sched_barrier(0);
        asm volatile("s_waitcnt lgkmcnt(0)" ::: "memory");
        if (kt < 11) {
            int ko = (kt + 1) * 32;
#pragma unroll
            for (int j = 0; j < 2; j++) glds16(sQ + bso[j] + ko, wsc + j * 512);
        }
        __builtin_amdgcn_sched_barrier(0);
#pragma unroll
        for (int a = 0; a < 2; a++)
#pragma unroll
            for (int b = 0; b < 4; b++)
                aq[a][b] = MFMA16(bq[a], af[b], aq[a][b]);
    }

    // ---- Q bounce: two 2KB rounds through scratch -> qf ----
    const float scl = 0.17677669529663687f;
    short8 qf[4];
#pragma unroll
    for (int jq = 0; jq < 2; jq++) {
#pragma unroll
        for (int a = 0; a < 2; a++) {
            float4 bv = *(const float4*)(bskip + wid * 32 + a * 16 + g4 * 4);
#pragma unroll
            for (int bb = 0; bb < 2; bb++) {
                int b = jq * 2 + bb;
                uint2 pk;
                pk.x = cvt2bf(aq[a][b][0] + bv.x * scl, aq[a][b][1] + bv.y * scl);
                pk.y = cvt2bf(aq[a][b][2] + bv.z * scl, aq[a][b][3] + bv.w * scl);
                int lr = bb * 16 + l15;
                int phys = (a * 2 + (g4 >> 1)) ^ (l15 & 3);
                *(uint2*)(wsc + lr * 32 + phys * 8 + (g4 & 1) * 4) = pk;
            }
        }
        lds_fence();
#pragma unroll
        for (int nn = 0; nn < 2; nn++)
            qf[jq * 2 + nn] = *(const short8*)(wsc + (nn * 16 + l15) * 32 +
                                               ((g4 ^ (l15 & 3)) * 8));
        lds_fence();
    }

    // ---- k prologue + B2 + gather xq -> A + B3 ----
#pragma unroll
    for (int j = 0; j < 2; j++) glds16(sK + bso[j], wsc + j * 512);
    __syncthreads();  // B2: all waves done reading A(skip)
    gatherA(xq);
    __syncthreads();  // B3

    // ---- k-GEMM (swapped) ----
    floatx4 ak[2][4];
#pragma unroll
    for (int a = 0; a < 2; a++)
#pragma unroll
        for (int b = 0; b < 4; b++)
#pragma unroll
            for (int r = 0; r < 4; r++) ak[a][b][r] = 0.f;
#pragma unroll
    for (int kt = 0; kt < 12; ++kt) {
        asm volatile("s_waitcnt vmcnt(0)" ::: "memory");
        const int choff = ((kt * 4 + g4) ^ al7) * 8;
        short8 af[4], bk[2];
#pragma unroll
        for (int b = 0; b < 4; b++)
            af[b] = *(const short8*)(smem + (b * 16 + l15) * 384 + choff);
#pragma unroll
        for (int a = 0; a < 2; a++)
            bk[a] = *(const short8*)(wsc + (a * 16 + l15) * 32 + brd);
        __builtin_amdgcn_sched_barrier(0);
        asm volatile("s_waitcnt lgkmcnt(0)" ::: "memory");
        if (kt < 11) {
            int ko = (kt + 1) * 32;
#pragma unroll
            for (int j = 0; j < 2; j++) glds16(sK + bso[j] + ko, wsc + j * 512);
        }
        __builtin_amdgcn_sched_barrier(0);
#pragma unroll
        for (int a = 0; a < 2; a++)
#pragma unroll
            for (int b = 0; b < 4; b++)
                ak[a][b] = MFMA16(bk[a], af[b], ak[a][b]);
    }

    // ---- K bounce: two 2KB rounds through scratch -> kf ----
    short8 kf[4];
#pragma unroll
    for (int jq = 0; jq < 2; jq++) {
#pragma unroll
        for (int a = 0; a < 2; a++) {
            float4 bv = *(const float4*)(bqkv + wid * 32 + a * 16 + g4 * 4);
#pragma unroll
            for (int bb = 0; bb < 2; bb++) {
                int b = jq * 2 + bb;
                uint2 pk;
                pk.x = cvt2bf(ak[a][b][0] + bv.x, ak[a][b][1] + bv.y);
                pk.y = cvt2bf(ak[a][b][2] + bv.z, ak[a][b][3] + bv.w);
                int lr = bb * 16 + l15;
                int phys = (a * 2 + (g4 >> 1)) ^ (l15 & 3);
                *(uint2*)(wsc + lr * 32 + phys * 8 + (g4 & 1) * 4) = pk;
            }
        }
        lds_fence();
#pragma unroll
        for (int nn = 0; nn < 2; nn++)
            kf[jq * 2 + nn] = *(const short8*)(wsc + (nn * 16 + l15) * 32 +
                                               ((g4 ^ (l15 & 3)) * 8));
        lds_fence();
    }

    // ---- v prologue + v-GEMM (unswapped) ----
#pragma unroll
    for (int j = 0; j < 2; j++) glds16(sV + bso[j], wsc + j * 512);
    floatx4 av[2][4];
#pragma unroll
    for (int a = 0; a < 2; a++)
#pragma unroll
        for (int b = 0; b < 4; b++)
#pragma unroll
            for (int r = 0; r < 4; r++) av[a][b][r] = 0.f;
#pragma unroll
    for (int kt = 0; kt < 12; ++kt) {
        asm volatile("s_waitcnt vmcnt(0)" ::: "memory");
        const int choff = ((kt * 4 + g4) ^ al7) * 8;
        short8 af[4], bv2[2];
#pragma unroll
        for (int b = 0; b < 4; b++)
            af[b] = *(const short8*)(smem + (b * 16 + l15) * 384 + choff);
#pragma unroll
        for (int a = 0; a < 2; a++)
            bv2[a] = *(const short8*)(wsc + (a * 16 + l15) * 32 + brd);
        __builtin_amdgcn_sched_barrier(0);
        asm volatile("s_waitcnt lgkmcnt(0)" ::: "memory");
        if (kt < 11) {
            int ko = (kt + 1) * 32;
#pragma unroll
            for (int j = 0; j < 2; j++) glds16(sV + bso[j] + ko, wsc + j * 512);
        }
        __builtin_amdgcn_sched_barrier(0);
#pragma unroll
        for (int a = 0; a < 2; a++)
#pragma unroll
            for (int b = 0; b < 4; b++)
                av[a][b] = MFMA16(af[b], bv2[a], av[a][b]);
    }
    __syncthreads();  // B4: all waves done reading A(query)

    // ---- V bounce: V^T[32d][64t] swizzled into A-slice -> vf ----
#pragma unroll
    for (int a = 0; a < 2; a++) {
        float bvs = bqkv[384 + wid * 32 + a * 16 + l15];
#pragma unroll
        for (int b = 0; b < 4; b++) {
            uint2 pk;
            pk.x = cvt2bf(av[a][b][0] + bvs, av[a][b][1] + bvs);
            pk.y = cvt2bf(av[a][b][2] + bvs, av[a][b][3] + bvs);
            int tch = b * 2 + (g4 >> 1);
            *(uint2*)(pA + (a * 16 + l15) * 64 +
                      ((tch ^ (l15 & 7)) * 8) + (g4 & 1) * 4) = pk;
        }
    }
    lds_fence();
    short8 vf[2][2];
#pragma unroll
    for (int ma = 0; ma < 2; ma++)
#pragma unroll
        for (int ks = 0; ks < 2; ks++)
            vf[ma][ks] = *(const short8*)(pA + (ma * 16 + l15) * 64 +
                                          (((ks * 4 + g4) ^ (l15 & 7)) * 8));
    lds_fence();

    // ---- attention: S^T = mfma(K,Q) ----
    floatx4 st[4][4];
#pragma unroll
    for (int mi = 0; mi < 4; mi++)
#pragma unroll
        for (int nj = 0; nj < 4; nj++)
#pragma unroll
            for (int r = 0; r < 4; r++) st[mi][nj][r] = 0.f;
#pragma unroll
    for (int mi = 0; mi < 4; mi++)
#pragma unroll
        for (int nj = 0; nj < 4; nj++)
            st[mi][nj] = MFMA16(kf[mi], qf[nj], st[mi][nj]);

    const float* bb = bias64 + wid * 4096;
#pragma unroll
    for (int nj = 0; nj < 4; nj++) {
        int i = nj * 16 + l15;
#pragma unroll
        for (int mi = 0; mi < 4; mi++) {
            floatx4 b4 = *(const floatx4*)(bb + i * 64 + mi * 16 + g4 * 4);
            st[mi][nj] += b4;
        }
    }

    if (wy == 11 || wx == 11) {
        int wy11 = (wy == 11), wx11 = (wx == 11);
        int ri[4];
#pragma unroll
        for (int nj = 0; nj < 4; nj++) {
            int t = nj * 16 + l15;
            int hh = wy11 ? (((t >> 3) >= 4) ? 2 : 1) : 0;
            int ww = wx11 ? (((t & 7) >= 4) ? 2 : 1) : 0;
            ri[nj] = hh * 3 + ww;
        }
#pragma unroll
        for (int mi = 0; mi < 4; mi++)
#pragma unroll
            for (int r = 0; r < 4; r++) {
                int t = mi * 16 + g4 * 4 + r;
                int hh = wy11 ? (((t >> 3) >= 4) ? 2 : 1) : 0;
                int ww = wx11 ? (((t & 7) >= 4) ? 2 : 1) : 0;
                int rk = hh * 3 + ww;
#pragma unroll
                for (int nj = 0; nj < 4; nj++)
                    if (rk != ri[nj]) st[mi][nj][r] -= 100.0f;
            }
    }

    float rden[4];
#pragma unroll
    for (int nj = 0; nj < 4; nj++) {
        float m = -1e30f;
#pragma unroll
        for (int mi = 0; mi < 4; mi++)
#pragma unroll
            for (int r = 0; r < 4; r++) m = fmaxf(m, st[mi][nj][r]);
        m = fmaxf(m, __shfl_xor(m, 16));
        m = fmaxf(m, __shfl_xor(m, 32));
        float s = 0.f;
#pragma unroll
        for (int mi = 0; mi < 4; mi++)
#pragma unroll
            for (int r = 0; r < 4; r++) {
                float p = __expf(st[mi][nj][r] - m);
                st[mi][nj][r] = p;
                s += p;
            }
        s += __shfl_xor(s, 16);
        s += __shfl_xor(s, 32);
        rden[nj] = 1.0f / s;
    }

    // ---- P halves through A-slice + PV ----
    floatx4 o[2][4];
#pragma unroll
    for (int ma = 0; ma < 2; ma++)
#pragma unroll
        for (int nj = 0; nj < 4; nj++)
#pragma unroll
            for (int r = 0; r < 4; r++) o[ma][nj][r] = 0.f;
#pragma unroll
    for (int ks = 0; ks < 2; ks++) {
#pragma unroll
        for (int mm = 0; mm < 2; mm++) {
            int mi = ks * 2 + mm;
#pragma unroll
            for (int nj = 0; nj < 4; nj++) {
                uint2 pk;
                pk.x = cvt2bf(st[mi][nj][0], st[mi][nj][1]);
                pk.y = cvt2bf(st[mi][nj][2], st[mi][nj][3]);
                int phys = (mm * 2 + (g4 >> 1)) ^ (l15 & 3);
                *(uint2*)(pA + (nj * 16 + l15) * 32 + phys * 8 + (g4 & 1) * 4) = pk;
            }
        }
        lds_fence();
        short8 pb[4];
#pragma unroll
        for (int nj = 0; nj < 4; nj++)
            pb[nj] = *(const short8*)(pA + (nj * 16 + l15) * 32 +
                                      ((g4 ^ (l15 & 3)) * 8));
#pragma unroll
        for (int ma = 0; ma < 2; ma++)
#pragma unroll
            for (int nj = 0; nj < 4; nj++)
                o[ma][nj] = MFMA16(vf[ma][ks], pb[nj], o[ma][nj]);
        lds_fence();
    }

    // ---- proj prologue (wave-private scratch) ----
#pragma unroll
    for (int j = 0; j < 2; j++) glds16(sP + bso[j], wsc + j * 512);

    __syncthreads();  // B5a: all waves done with their P-slices

    // ---- out -> A-region (chunk-swizzled [t][384]) ----
#pragma unroll
    for (int ma = 0; ma < 2; ma++)
#pragma unroll
        for (int nj = 0; nj < 4; nj++) {
            int i = nj * 16 + l15;
            uint2 pk;
            pk.x = cvt2bf(o[ma][nj][0] * rden[nj], o[ma][nj][1] * rden[nj]);
            pk.y = cvt2bf(o[ma][nj][2] * rden[nj], o[ma][nj][3] * rden[nj]);
            int ch = wid * 4 + ma * 2 + (g4 >> 1);
            *(uint2*)(smem + i * 384 + ((ch ^ (i & 7)) * 8) + (g4 & 1) * 4) = pk;
        }
    __syncthreads();  // B5

    // ---- proj GEMM (swapped; single-buffered staging) ----
    floatx4 ap[2][4];
#pragma unroll
    for (int a = 0; a < 2; a++)
#pragma unroll
        for (int b = 0; b < 4; b++)
#pragma unroll
            for (int r = 0; r < 4; r++) ap[a][b][r] = 0.f;
#pragma unroll
    for (int kt = 0; kt < 12; ++kt) {
        asm volatile("s_waitcnt vmcnt(0)" ::: "memory");
        const int choff = ((kt * 4 + g4) ^ al7) * 8;
        short8 af[4], bp[2];
#pragma unroll
        for (int b = 0; b < 4; b++)
            af[b] = *(const short8*)(smem + (b * 16 + l15) * 384 + choff);
#pragma unroll
        for (int a = 0; a < 2; a++)
            bp[a] = *(const short8*)(wsc + (a * 16 + l15) * 32 + brd);
        __builtin_amdgcn_sched_barrier(0);
        asm volatile("s_waitcnt lgkmcnt(0)" ::: "memory");
        if (kt < 11) {
            int ko = (kt + 1) * 32;
#pragma unroll
            for (int j = 0; j < 2; j++) glds16(sP + bso[j] + ko, wsc + j * 512);
        }
        __builtin_amdgcn_sched_barrier(0);
#pragma unroll
        for (int a = 0; a < 2; a++)
#pragma unroll
            for (int b = 0; b < 4; b++)
                ap[a][b] = MFMA16(bp[a], af[b], ap[a][b]);
    }
    __syncthreads();  // B6: all waves done reading A(out)

    // ---- fp32 out: two rounds through A-slice -> full-line stores ----
    float* fsc = (float*)pA;  // [32][32] fp32 per round
#pragma unroll
    for (int h = 0; h < 2; h++) {
#pragma unroll
        for (int a = 0; a < 2; a++) {
            float4 bv = *(const float4*)(bproj + wid * 32 + a * 16 + g4 * 4);
#pragma unroll
            for (int bb = 0; bb < 2; bb++) {
                int b = h * 2 + bb;
                int lr = bb * 16 + l15;
                int phys = (a * 4 + g4) ^ (lr & 7);
                floatx4 ov = ap[a][b];
                ov[0] += bv.x; ov[1] += bv.y; ov[2] += bv.z; ov[3] += bv.w;
                *(floatx4*)(fsc + lr * 32 + phys * 4) = ov;
            }
        }
        lds_fence();
        {
            const int r8 = lane >> 3, c8 = lane & 7;
#pragma unroll
            for (int it = 0; it < 4; it++) {
                int lr = it * 8 + r8;
                floatx4 ov = *(const floatx4*)(fsc + lr * 32 + ((c8 ^ r8) * 4));
                int trow = h * 32 + lr;
                int yy = wy * 8 + (trow >> 3) + 4; if (yy >= 96) yy -= 96;
                int xx = wx * 8 + (trow & 7) + 4;  if (xx >= 96) xx -= 96;
                *(floatx4*)(&out[((size_t)b_img * 9216 + yy * 96 + xx) * 384 +
                                 wid * 32 + c8 * 4]) = ov;
            }
        }
        lds_fence();
    }
}

// ---------------- launcher ----------------
extern "C" void kernel_launch(void* const* d_in, const int* in_sizes, int n_in,
                              void* d_out, int out_size, void* d_ws, size_t ws_size,
                              hipStream_t stream) {
    const float* query = (const float*)d_in[0];
    const float* skipq = (const float*)d_in[1];
    const float* Wqkv  = (const float*)d_in[2];
    const float* bqkv  = (const float*)d_in[3];
    const float* Wskip = (const float*)d_in[4];
    const float* bskip = (const float*)d_in[5];
    const float* rpb   = (const float*)d_in[6];
    const float* Wproj = (const float*)d_in[7];
    const float* bproj = (const float*)d_in[8];
    float* out = (float*)d_out;

    int M = in_sizes[0] / 384;   // total tokens = 147456 for B=16
    int nwin = M / 64;           // 2304

    char* ws = (char*)d_ws;
    size_t off = 0;
    auto alloc = [&](size_t bytes) -> void* {
        void* p = ws + off;
        off = (off + bytes + 255) & ~(size_t)255;
        return p;
    };
    short* Wt     = (short*)alloc((size_t)1152 * 384 * 2);
    short* WtP    = (short*)alloc((size_t)384 * 384 * 2);
    float* bias64 = (float*)alloc((size_t)12 * 64 * 64 * 4);
    (void)ws_size;

    hipLaunchKernelGGL(prep_wt, dim3(216), dim3(256), 0, stream, Wqkv, Wskip, Wt);
    hipLaunchKernelGGL(prep_wtp, dim3(72), dim3(256), 0, stream, Wproj, WtP);
    hipLaunchKernelGGL(prep_bias, dim3(192), dim3(256), 0, stream, rpb, bias64);
    hipLaunchKernelGGL(fused_win, dim3(nwin), dim3(768), 0, stream,
                       query, skipq, Wt, WtP, bqkv, bskip, bproj, bias64, out);
}